// Round 3
// baseline (2928.353 us; speedup 1.0000x reference)
//
#include <hip/hip_runtime.h>
#include <hip/hip_bf16.h>
#include <stdint.h>

// Shapes (fixed by the problem)
#define BB 32
#define TT 128
#define VV 16000
#define EE 512
#define HH 1024
#define FF 2048

typedef __attribute__((ext_vector_type(8))) short short8;   // 8 bf16 = 4 VGPRs (MFMA A/B frag)
typedef __attribute__((ext_vector_type(4))) float floatx4;  // MFMA C/D frag

static __device__ __forceinline__ float bf2f(ushort u) {
    union { unsigned int i; float f; } v; v.i = ((unsigned int)u) << 16; return v.f;
}
static __device__ __forceinline__ ushort f2bf(float f) {
    union { float f; unsigned int i; } v; v.f = f;
    unsigned int x = v.i;
    return (ushort)((x + 0x7fffu + ((x >> 16) & 1u)) >> 16);   // RNE
}
static __device__ __forceinline__ float sigf(float x) {
    return 1.0f / (1.0f + __expf(-x));
}

// read 8 consecutive elements as a bf16 MFMA fragment, from bf16 or fp32 storage
static __device__ __forceinline__ short8 ld8(const char* p, int f32) {
    if (f32) {
        const float4 a = *(const float4*)p;
        const float4 b = *(const float4*)(p + 16);
        short8 r;
        r[0] = (short)f2bf(a.x); r[1] = (short)f2bf(a.y);
        r[2] = (short)f2bf(a.z); r[3] = (short)f2bf(a.w);
        r[4] = (short)f2bf(b.x); r[5] = (short)f2bf(b.y);
        r[6] = (short)f2bf(b.z); r[7] = (short)f2bf(b.w);
        return r;
    }
    return *(const short8*)p;
}
static __device__ __forceinline__ float ldsc(const char* b, int i, int f32) {
    return f32 ? ((const float*)b)[i] : bf2f(((const ushort*)b)[i]);
}

// ---------------------------------------------------------------------------
// Detect storage dtype of float inputs by sampling fc_W as ushorts.
// bf16 storage: every ushort decodes to |x| ~ 0.02 (never 0, never huge).
// fp32 storage: even ushorts are fp32 low-halves -> exactly 0 (bf16-quantized
// values) or random-exponent garbage (~47% |x|>100). flag=1 means fp32.
__global__ void detect_kernel(const ushort* __restrict__ w, int* __restrict__ flag) {
    if (threadIdx.x == 0 && blockIdx.x == 0) {
        int cnt = 0;
        for (int i = 0; i < 512; i += 2) {
            ushort u = w[i];
            float x = bf2f(u);
            float ax = x < 0.f ? -x : x;
            if (u == 0u || u == 0x8000u || ax > 100.f) cnt++;
        }
        *flag = (cnt >= 8) ? 1 : 0;
    }
}

// generic elementwise convert (bf16|fp32 -> bf16), used once for W_hh
__global__ void conv_kernel(const char* __restrict__ in, ushort* __restrict__ out,
                            int n, const int* __restrict__ flagp) {
    int i = blockIdx.x * 256 + threadIdx.x;
    if (i >= n) return;
    int fl = *flagp;
    out[i] = fl ? f2bf(((const float*)in)[i]) : ((const ushort*)in)[i];
}

// pooled[b*F+f] = mean over 7x7 of features (bf16 out)
__global__ void pool_kernel(const char* __restrict__ feats, ushort* __restrict__ pooled,
                            const int* __restrict__ flagp) {
    int p = blockIdx.x * 256 + threadIdx.x;        // 0 .. B*F-1 = 65535
    int fl = *flagp;
    float s = 0.f;
    if (fl) {
        const float* src = (const float*)feats + (size_t)p * 49;
        #pragma unroll
        for (int i = 0; i < 49; i++) s += src[i];
    } else {
        const ushort* src = (const ushort*)feats + (size_t)p * 49;
        #pragma unroll
        for (int i = 0; i < 49; i++) s += bf2f(src[i]);
    }
    pooled[p] = f2bf(s * (1.0f / 49.0f));
}

// init[:,1024:] (bf16, internal) -> c (fp32)
__global__ void csplit_kernel(const ushort* __restrict__ initb, float* __restrict__ c) {
    int i = blockIdx.x * 256 + threadIdx.x;        // 0..32767
    int b = i >> 10, j = i & 1023;
    c[i] = bf2f(initb[b * 2048 + 1024 + j]);
}

// ridx[row] = embedding row for logical GEMM row (b*T+t)
__global__ void ridx_kernel(const int* __restrict__ reports, int* __restrict__ ridx) {
    int row = blockIdx.x * 256 + threadIdx.x;      // 0..4095
    int b = row >> 7, t = row & 127;
    ridx[row] = (t == 0) ? 1 : reports[b * TT + t - 1];
}

// ---------------------------------------------------------------------------
// Generic GEMM: C(M,N) = A(M,K) @ Bm(N,K)^T + bias1 [+ bias2].
// A/B/bias may be external (dtype per flag) or internal bf16. Output bf16
// unless (oext && flag) -> fp32. Optional ridx = A-row indirection.
// 128x128 tile, BK=32, 4 waves (2x2), 4x4 16x16x32 MFMAs per wave.
__global__ __launch_bounds__(256) void gemm_bf16(
    const char* __restrict__ A, const char* __restrict__ Bm,
    const int* __restrict__ ridx,
    const char* __restrict__ bias1, const char* __restrict__ bias2,
    char* __restrict__ C, int M, int N, int K,
    const int* __restrict__ flagp, int aext, int bext, int oext)
{
    __shared__ ushort As[128 * 32];
    __shared__ ushort Bs[128 * 32];
    const int fl = *flagp;
    const int af32 = aext & fl, bf32 = bext & fl;
    const size_t eA = af32 ? 4 : 2, eB = bf32 ? 4 : 2;

    const int tid  = threadIdx.x;
    const int wave = tid >> 6, lane = tid & 63;
    const int ln = lane & 15, quad = lane >> 4;
    const int wm = wave & 1, wn = wave >> 1;
    const int bm = blockIdx.y, bn = blockIdx.x;

    floatx4 acc[4][4] = {};

    // 512 8-elem chunks per tile (128 rows x 4 k-chunks); thread handles c0,c1.
    const int c0 = tid, c1 = 256 + tid;
    int lr0 = bm * 128 + (c0 >> 2); if (lr0 >= M) lr0 = M - 1;
    int lr1 = bm * 128 + (c1 >> 2); if (lr1 >= M) lr1 = M - 1;
    const int rA0 = ridx ? ridx[lr0] : lr0;
    const int rA1 = ridx ? ridx[lr1] : lr1;
    const int rB0 = bn * 128 + (c0 >> 2);
    const int rB1 = bn * 128 + (c1 >> 2);
    const char* gA0 = A  + ((size_t)rA0 * K + (c0 & 3) * 8) * eA;
    const char* gA1 = A  + ((size_t)rA1 * K + (c1 & 3) * 8) * eA;
    const char* gB0 = Bm + ((size_t)rB0 * K + (c0 & 3) * 8) * eB;
    const char* gB1 = Bm + ((size_t)rB1 * K + (c1 & 3) * 8) * eB;

    for (int k0 = 0; k0 < K; k0 += 32) {
        short8 va0 = ld8(gA0 + (size_t)k0 * eA, af32);
        short8 va1 = ld8(gA1 + (size_t)k0 * eA, af32);
        short8 vb0 = ld8(gB0 + (size_t)k0 * eB, bf32);
        short8 vb1 = ld8(gB1 + (size_t)k0 * eB, bf32);
        __syncthreads();                       // prior iter's LDS reads complete
        *(short8*)(As + c0 * 8) = va0;
        *(short8*)(As + c1 * 8) = va1;
        *(short8*)(Bs + c0 * 8) = vb0;
        *(short8*)(Bs + c1 * 8) = vb1;
        __syncthreads();                       // staging visible

        short8 af[4], bfg[4];
        #pragma unroll
        for (int i = 0; i < 4; i++)
            af[i] = *(const short8*)(As + (wm * 64 + i * 16 + ln) * 32 + quad * 8);
        #pragma unroll
        for (int i = 0; i < 4; i++)
            bfg[i] = *(const short8*)(Bs + (wn * 64 + i * 16 + ln) * 32 + quad * 8);
        #pragma unroll
        for (int i = 0; i < 4; i++)
            #pragma unroll
            for (int j = 0; j < 4; j++)
                acc[i][j] = __builtin_amdgcn_mfma_f32_16x16x32_bf16(af[i], bfg[j], acc[i][j], 0, 0, 0);
    }

    // epilogue: C/D layout col=lane&15, row=quad*4+reg (m89-verified)
    const int of32 = oext & fl;
    const int col_base = bn * 128 + wn * 64;
    const int row_base = bm * 128 + wm * 64;
    #pragma unroll
    for (int j = 0; j < 4; j++) {
        const int col = col_base + j * 16 + ln;
        float bb = ldsc(bias1, col, fl);
        if (bias2) bb += ldsc(bias2, col, fl);
        #pragma unroll
        for (int i = 0; i < 4; i++) {
            const int row0 = row_base + i * 16 + quad * 4;
            #pragma unroll
            for (int r = 0; r < 4; r++) {
                const int row = row0 + r;
                if (row < M) {
                    float v = acc[i][j][r] + bb;
                    if (of32) ((float*)C)[(size_t)row * N + col] = v;
                    else      ((ushort*)C)[(size_t)row * N + col] = f2bf(v);
                }
            }
        }
    }
}

// ---------------------------------------------------------------------------
// One LSTM step. 64 blocks (jt), 4 waves = 4 gates (i,f,g,o). All inputs are
// internal bf16 buffers (Whh pre-converted), c is fp32.
__global__ __launch_bounds__(256) void step_kernel(
    const ushort* __restrict__ h_prev, int h_stride,
    const ushort* __restrict__ gx, const ushort* __restrict__ Whh,
    float* __restrict__ c, ushort* __restrict__ hs, int t)
{
    __shared__ float gbuf[4][32][16];
    const int jt = blockIdx.x;
    const int tid = threadIdx.x;
    const int w = tid >> 6, lane = tid & 63;
    const int ln = lane & 15, quad = lane >> 4;

    floatx4 acc[2] = {};
    // B fragment for lane: row n = w*1024 + jt*16 + ln, k = kc*32 + quad*8 + j
    const ushort* wb  = Whh + (size_t)(w * 1024 + jt * 16 + ln) * HH + quad * 8;
    const ushort* a0p = h_prev + (size_t)(ln)      * h_stride + quad * 8;
    const ushort* a1p = h_prev + (size_t)(16 + ln) * h_stride + quad * 8;

    #pragma unroll 4
    for (int kc = 0; kc < 32; kc++) {
        short8 b  = *(const short8*)(wb  + kc * 32);
        short8 a0 = *(const short8*)(a0p + kc * 32);
        short8 a1 = *(const short8*)(a1p + kc * 32);
        acc[0] = __builtin_amdgcn_mfma_f32_16x16x32_bf16(a0, b, acc[0], 0, 0, 0);
        acc[1] = __builtin_amdgcn_mfma_f32_16x16x32_bf16(a1, b, acc[1], 0, 0, 0);
    }

    const int n = w * 1024 + jt * 16 + ln;
    #pragma unroll
    for (int mi = 0; mi < 2; mi++) {
        #pragma unroll
        for (int r = 0; r < 4; r++) {
            const int b_ = mi * 16 + quad * 4 + r;
            float v = acc[mi][r] + bf2f(gx[((size_t)b_ * TT + t) * 4096 + n]);
            gbuf[w][b_][ln] = v;
        }
    }
    __syncthreads();

    for (int p = tid; p < 512; p += 256) {
        const int b_ = p >> 4, jl = p & 15;
        const float iv = gbuf[0][b_][jl];
        const float fv = gbuf[1][b_][jl];
        const float gv = gbuf[2][b_][jl];
        const float ov = gbuf[3][b_][jl];
        const int cidx = b_ * HH + jt * 16 + jl;
        float cn = sigf(fv) * c[cidx] + sigf(iv) * tanhf(gv);
        c[cidx] = cn;
        float hn = sigf(ov) * tanhf(cn);
        hs[((size_t)b_ * TT + t) * HH + jt * 16 + jl] = f2bf(hn);
    }
}

// ---------------------------------------------------------------------------
extern "C" void kernel_launch(void* const* d_in, const int* in_sizes, int n_in,
                              void* d_out, int out_size, void* d_ws, size_t ws_size,
                              hipStream_t stream) {
    const char* feats   = (const char*)d_in[0];
    const int*  reports = (const int*) d_in[1];
    const char* fcW     = (const char*)d_in[2];
    const char* fcb     = (const char*)d_in[3];
    const char* emb     = (const char*)d_in[4];
    const char* Wih     = (const char*)d_in[5];
    const char* Whh     = (const char*)d_in[6];
    const char* bih     = (const char*)d_in[7];
    const char* bhh     = (const char*)d_in[8];
    const char* Wv      = (const char*)d_in[9];
    const char* bv      = (const char*)d_in[10];

    // workspace layout (~48.8 MB total), big-first, 16B-aligned
    char* p = (char*)d_ws;
    ushort* gx     = (ushort*)p; p += (size_t)BB * TT * 4096 * 2;     // 32 MB
    ushort* hs     = (ushort*)p; p += (size_t)BB * TT * HH * 2;       // 8 MB
    ushort* Whhb   = (ushort*)p; p += (size_t)4096 * HH * 2;          // 8 MB
    ushort* pooled = (ushort*)p; p += (size_t)BB * FF * 2;            // 128 KB
    ushort* initb  = (ushort*)p; p += (size_t)BB * 2048 * 2;          // 128 KB
    float*  cbuf   = (float*) p; p += (size_t)BB * HH * 4;            // 128 KB
    int*    ridx   = (int*)   p; p += (size_t)BB * TT * 4;            // 16 KB
    int*    flag   = (int*)   p; p += 16;

    detect_kernel<<<1, 64, 0, stream>>>((const ushort*)fcW, flag);
    conv_kernel  <<<16384, 256, 0, stream>>>(Whh, Whhb, 4096 * HH, flag);
    pool_kernel  <<<256, 256, 0, stream>>>(feats, pooled, flag);
    ridx_kernel  <<<16,  256, 0, stream>>>(reports, ridx);

    gemm_bf16<<<dim3(16, 1), 256, 0, stream>>>((const char*)pooled, fcW, nullptr,
                                               fcb, nullptr, (char*)initb,
                                               32, 2048, 2048, flag, 0, 1, 0);
    csplit_kernel<<<128, 256, 0, stream>>>(initb, cbuf);
    // gates_x = emb[in_idx] @ W_ih^T + (b_ih + b_hh), gather fused via ridx
    gemm_bf16<<<dim3(32, 32), 256, 0, stream>>>(emb, Wih, ridx, bih, bhh,
                                                (char*)gx, BB * TT, 4096, EE,
                                                flag, 1, 1, 0);

    for (int t = 0; t < TT; t++) {
        const ushort* hp = (t == 0) ? initb : (hs + (size_t)(t - 1) * HH);
        const int hstride = (t == 0) ? 2048 : TT * HH;
        step_kernel<<<64, 256, 0, stream>>>(hp, hstride, gx, Whhb, cbuf, hs, t);
    }

    gemm_bf16<<<dim3(125, 32), 256, 0, stream>>>((const char*)hs, Wv, nullptr,
                                                 bv, nullptr, (char*)d_out,
                                                 BB * TT, VV, HH, flag, 0, 1, 1);
}